// Round 19
// baseline (380.609 us; speedup 1.0000x reference)
//
#include <hip/hip_runtime.h>
#include <hip/hip_bf16.h>
#include <math.h>

#define NBLK 512
#define MAXNC 512     // supports N up to 131072 (256 nodes per coarse bucket)
#define STAGE_CAP 12512  // >= chunk = ceil(E/NBLK) 4-aligned (E=6.4M -> 12500)
#define BCAP 26624       // per-bucket padded capacity (expected ~20.2K, 25 sigma margin)

typedef float vfloat4 __attribute__((ext_vector_type(4)));
typedef unsigned int uint32;

__device__ __forceinline__ float bf_lo(uint32 u) { return __uint_as_float(u << 16); }
__device__ __forceinline__ float bf_hi(uint32 u) { return __uint_as_float(u & 0xFFFF0000u); }
__device__ __forceinline__ uint32 f2b(float f) {  // fp32 -> bf16 bits, RNE
    uint32 u = __float_as_uint(f);
    return (u + 0x7FFFu + ((u >> 16) & 1u)) >> 16;
}
__device__ __forceinline__ uint32 pack2(float a, float b) { return f2b(a) | (f2b(b) << 16); }

// ---------------- init: bucket cursors ----------------
__global__ void k_init(int* __restrict__ gcur, int* __restrict__ totReal, int nc) {
    int i = blockIdx.x * blockDim.x + threadIdx.x;
    if (i < nc) { gcur[i] = i * BCAP; totReal[i] = 0; }
}

// ---------------- fill: local hist + LDS stage + atomic padded reservation + full-line flush ----------------
__global__ __launch_bounds__(256, 2)
void k_fill(const int* __restrict__ src, const int* __restrict__ dst,
            int* __restrict__ gcur, int* __restrict__ totReal,
            int* __restrict__ bucketed, int nE, int nc, int chunk) {
    __shared__ int stage[STAGE_CAP];
    __shared__ int lbeg[MAXNC];   // holds local hist, then local begin offsets
    __shared__ int lcur[MAXNC];
    __shared__ int sc[256];
    int b = blockIdx.x, t = threadIdx.x;
    for (int i = t; i < nc; i += 256) lbeg[i] = 0;
    __syncthreads();

    int c0 = b * chunk, c1 = min(nE, c0 + chunk);
    int nv = (c1 > c0) ? ((c1 - c0) >> 2) : 0;
    int rem = (c1 > c0) ? ((c1 - c0) & 3) : 0;

    // pass 1: local histogram (also warms L2 for pass 2)
    {
        const int4* d4 = (const int4*)(dst + c0);
        for (int i = t; i < nv; i += 256) {
            int4 dd = d4[i];
            atomicAdd(&lbeg[dd.x >> 8], 1);
            atomicAdd(&lbeg[dd.y >> 8], 1);
            atomicAdd(&lbeg[dd.z >> 8], 1);
            atomicAdd(&lbeg[dd.w >> 8], 1);
        }
        if (t < rem) atomicAdd(&lbeg[dst[c0 + (nv << 2) + t] >> 8], 1);
    }
    __syncthreads();

    // local exclusive scan over nc buckets (pairs per thread)
    int v0 = (2 * t < nc) ? lbeg[2 * t] : 0;
    int v1 = (2 * t + 1 < nc) ? lbeg[2 * t + 1] : 0;
    int s = v0 + v1;
    sc[t] = s;
    __syncthreads();
    for (int d = 1; d < 256; d <<= 1) {
        int x = (t >= d) ? sc[t - d] : 0;
        __syncthreads();
        sc[t] += x;
        __syncthreads();
    }
    int excl = sc[t] - s;
    if (2 * t < nc) { lbeg[2 * t] = excl; lcur[2 * t] = excl; }
    if (2 * t + 1 < nc) { lbeg[2 * t + 1] = excl + v0; lcur[2 * t + 1] = excl + v0; }
    __syncthreads();

    // pass 2: stage entries into LDS
    {
        const int4* d4 = (const int4*)(dst + c0);
        const int4* s4 = (const int4*)(src + c0);
        for (int i = t; i < nv; i += 256) {
            int4 dd = d4[i];
            int4 ss = s4[i];
            int pos;
            pos = atomicAdd(&lcur[dd.x >> 8], 1); stage[pos] = ss.x | ((dd.x & 255) << 17);
            pos = atomicAdd(&lcur[dd.y >> 8], 1); stage[pos] = ss.y | ((dd.y & 255) << 17);
            pos = atomicAdd(&lcur[dd.z >> 8], 1); stage[pos] = ss.z | ((dd.z & 255) << 17);
            pos = atomicAdd(&lcur[dd.w >> 8], 1); stage[pos] = ss.w | ((dd.w & 255) << 17);
        }
        if (t < rem) {
            int e = c0 + (nv << 2) + t;
            int d = dst[e];
            int pos = atomicAdd(&lcur[d >> 8], 1);
            stage[pos] = src[e] | ((d & 255) << 17);
        }
    }
    __syncthreads();

    // pass 3: flush per bucket; reserve padded slots atomically (16-aligned -> full lines)
    for (int c = t; c < nc; c += 256) {
        int lo = lbeg[c];
        int cnt = lcur[c] - lo;
        if (cnt <= 0) continue;
        int padded = (cnt + 15) & ~15;
        int g = atomicAdd(&gcur[c], padded);
        atomicAdd(&totReal[c], cnt);
        for (int i = 0; i < padded; i += 4) {
            int4 v;
            v.x = (i + 0 < cnt) ? stage[lo + i + 0] : -1;
            v.y = (i + 1 < cnt) ? stage[lo + i + 1] : -1;
            v.z = (i + 2 < cnt) ? stage[lo + i + 2] : -1;
            v.w = (i + 3 < cnt) ? stage[lo + i + 3] : -1;
            *(int4*)(bucketed + g + i) = v;
        }
    }
}

// ---------------- scanB: prefix of real totals -> rbase ----------------
__global__ void k_scanB(const int* __restrict__ totReal, int* __restrict__ rbase,
                        int* __restrict__ rowstart, int nE, int nc, int n) {
    __shared__ int sr[512];
    int t = threadIdx.x;
    int vr = (t < nc) ? totReal[t] : 0;
    sr[t] = vr;
    __syncthreads();
    for (int d = 1; d < 512; d <<= 1) {
        int xr = (t >= d) ? sr[t - d] : 0;
        __syncthreads();
        sr[t] += xr;
        __syncthreads();
    }
    if (t < nc) rbase[t] = sr[t] - vr;
    if (t == 0) rowstart[n] = nE;
}

// ---------------- fine: within-bucket sort to compact per-node CSR ----------------
__global__ void k_fine(const int* __restrict__ bucketed, const int* __restrict__ gcur,
                       const int* __restrict__ rbase,
                       int* __restrict__ csr, int* __restrict__ rowstart,
                       float* __restrict__ dinv, int n) {
    __shared__ int cnt[256];
    __shared__ int lrs[512];
    __shared__ int cur[256];
    int cb = blockIdx.x, t = threadIdx.x;  // 512 threads
    int e0 = cb * BCAP, e1 = gcur[cb];
    int r0 = rbase[cb];
    if (t < 256) cnt[t] = 0;
    __syncthreads();
    int nv = (e1 - e0) >> 2;
    const int4* b4 = (const int4*)(bucketed + e0);
    for (int i = t; i < nv; i += 512) {
        int4 en = b4[i];
        if (en.x >= 0) atomicAdd(&cnt[(en.x >> 17) & 255], 1);
        if (en.y >= 0) atomicAdd(&cnt[(en.y >> 17) & 255], 1);
        if (en.z >= 0) atomicAdd(&cnt[(en.z >> 17) & 255], 1);
        if (en.w >= 0) atomicAdd(&cnt[(en.w >> 17) & 255], 1);
    }
    __syncthreads();
    int my = (t < 256) ? cnt[t] : 0;
    lrs[t] = my;
    __syncthreads();
    for (int d = 1; d < 512; d <<= 1) {
        int x = (t >= d) ? lrs[t - d] : 0;
        __syncthreads();
        lrs[t] += x;
        __syncthreads();
    }
    if (t < 256) {
        int excl = lrs[t] - my;
        int node = cb * 256 + t;
        if (node < n) {
            rowstart[node] = r0 + excl;
            dinv[node] = rsqrtf((float)(my + 1));
        }
        cur[t] = r0 + excl;
    }
    __syncthreads();
    for (int i = t; i < nv; i += 512) {
        int4 en = b4[i];
        int pos;
        if (en.x >= 0) { pos = atomicAdd(&cur[(en.x >> 17) & 255], 1); csr[pos] = en.x & 0x1FFFF; }
        if (en.y >= 0) { pos = atomicAdd(&cur[(en.y >> 17) & 255], 1); csr[pos] = en.y & 0x1FFFF; }
        if (en.z >= 0) { pos = atomicAdd(&cur[(en.z >> 17) & 255], 1); csr[pos] = en.z & 0x1FFFF; }
        if (en.w >= 0) { pos = atomicAdd(&cur[(en.w >> 17) & 255], 1); csr[pos] = en.w & 0x1FFFF; }
    }
}

// ---------------- prescale: xs = dinv * x (fp32) + bf16 shadow ----------------
__global__ void k_prescale(const float* __restrict__ x, const float* __restrict__ dinv,
                           float* __restrict__ xs, uint32* __restrict__ xsb, int n) {
    int i = blockIdx.x * blockDim.x + threadIdx.x;
    if (i >= n) return;
    float di = dinv[i];
    const float4* xp = (const float4*)(x + (size_t)i * 16);
    float4* op = (float4*)(xs + (size_t)i * 16);
    uint32 pk[8];
#pragma unroll
    for (int q = 0; q < 4; ++q) {
        float4 v = xp[q];
        v.x *= di; v.y *= di; v.z *= di; v.w *= di;
        op[q] = v;
        pk[q * 2 + 0] = pack2(v.x, v.y);
        pk[q * 2 + 1] = pack2(v.z, v.w);
    }
    uint4* bp = (uint4*)(xsb + (size_t)i * 8);
    bp[0] = make_uint4(pk[0], pk[1], pk[2], pk[3]);
    bp[1] = make_uint4(pk[4], pk[5], pk[6], pk[7]);
}

// ---------------- agg: wave/node, 16 slots x 4 lanes, batch-4 bf16 gathers ----------------
__global__ void k_agg(const uint32* __restrict__ hb16, const int* __restrict__ csr,
                      const int* __restrict__ rowstart, float* __restrict__ agg, int n) {
    int wid = (blockIdx.x * blockDim.x + threadIdx.x) >> 6;
    if (wid >= n) return;
    int lane = threadIdx.x & 63;
    int q = lane >> 2;   // edge slot 0..15
    int c = lane & 3;    // feature quad
    int r0 = rowstart[wid], r1 = rowstart[wid + 1];
    int cnt = r1 - r0;
    const int* p = csr + r0 + q;
    int my = (cnt > q) ? ((cnt - q + 15) >> 4) : 0;
    const uint2* hb = (const uint2*)hb16;

    float av[4] = {0.f, 0.f, 0.f, 0.f};
    int t = 0;
    for (; t + 4 <= my; t += 4) {
        int s0 = __builtin_nontemporal_load(p + (t + 0) * 16);
        int s1 = __builtin_nontemporal_load(p + (t + 1) * 16);
        int s2 = __builtin_nontemporal_load(p + (t + 2) * 16);
        int s3 = __builtin_nontemporal_load(p + (t + 3) * 16);
        uint2 w0 = hb[(size_t)s0 * 4 + c];
        uint2 w1 = hb[(size_t)s1 * 4 + c];
        uint2 w2 = hb[(size_t)s2 * 4 + c];
        uint2 w3 = hb[(size_t)s3 * 4 + c];
        av[0] += (bf_lo(w0.x) + bf_lo(w1.x)) + (bf_lo(w2.x) + bf_lo(w3.x));
        av[1] += (bf_hi(w0.x) + bf_hi(w1.x)) + (bf_hi(w2.x) + bf_hi(w3.x));
        av[2] += (bf_lo(w0.y) + bf_lo(w1.y)) + (bf_lo(w2.y) + bf_lo(w3.y));
        av[3] += (bf_hi(w0.y) + bf_hi(w1.y)) + (bf_hi(w2.y) + bf_hi(w3.y));
    }
    if (t + 2 <= my) {
        int s0 = __builtin_nontemporal_load(p + (t + 0) * 16);
        int s1 = __builtin_nontemporal_load(p + (t + 1) * 16);
        uint2 w0 = hb[(size_t)s0 * 4 + c];
        uint2 w1 = hb[(size_t)s1 * 4 + c];
        av[0] += bf_lo(w0.x) + bf_lo(w1.x);
        av[1] += bf_hi(w0.x) + bf_hi(w1.x);
        av[2] += bf_lo(w0.y) + bf_lo(w1.y);
        av[3] += bf_hi(w0.y) + bf_hi(w1.y);
        t += 2;
    }
    if (t < my) {
        int s0 = __builtin_nontemporal_load(p + t * 16);
        uint2 w0 = hb[(size_t)s0 * 4 + c];
        av[0] += bf_lo(w0.x); av[1] += bf_hi(w0.x);
        av[2] += bf_lo(w0.y); av[3] += bf_hi(w0.y);
    }
#pragma unroll
    for (int m = 4; m <= 32; m <<= 1) {
#pragma unroll
        for (int j = 0; j < 4; ++j) av[j] += __shfl_xor(av[j], m);
    }
    if (q == 0) {
        vfloat4 o = {av[0], av[1], av[2], av[3]};
        __builtin_nontemporal_store(o, (vfloat4*)(agg + (size_t)wid * 16 + c * 4));
    }
}

// ---------------- post: 4 threads/node, GEMM + activation; writes fp32 + bf16 shadow ----------------
template <int MODE>
__global__ void k_post(const float* __restrict__ agg, const float* __restrict__ hin,
                       const int* __restrict__ rowstart, const float* __restrict__ dinv,
                       const float* __restrict__ Wa, const float* __restrict__ ba,
                       const float* __restrict__ Wb,
                       float* __restrict__ hout, uint32* __restrict__ hb16out, int n) {
    int idx = blockIdx.x * blockDim.x + threadIdx.x;
    int node = idx >> 2;
    if (node >= n) return;
    int t4 = idx & 3;
    int lane = threadIdx.x & 63;
    int lbase = lane & 60;

    float4 av = *(const float4*)(agg + (size_t)node * 16 + t4 * 4);
    float4 sv = *(const float4*)(hin + (size_t)node * 16 + t4 * 4);

    float a[16], s[16];
#pragma unroll
    for (int g = 0; g < 4; ++g) {
        a[g * 4 + 0] = __shfl(av.x, lbase + g);
        a[g * 4 + 1] = __shfl(av.y, lbase + g);
        a[g * 4 + 2] = __shfl(av.z, lbase + g);
        a[g * 4 + 3] = __shfl(av.w, lbase + g);
        s[g * 4 + 0] = __shfl(sv.x, lbase + g);
        s[g * 4 + 1] = __shfl(sv.y, lbase + g);
        s[g * 4 + 2] = __shfl(sv.z, lbase + g);
        s[g * 4 + 3] = __shfl(sv.w, lbase + g);
    }

    int fo = t4 * 4;
    float yv[4];
    if (MODE == 0) {
        float di = dinv[node];
#pragma unroll
        for (int k = 0; k < 16; ++k) a[k] = di * (a[k] + s[k]);
#pragma unroll
        for (int j = 0; j < 4; ++j) yv[j] = ba[fo + j];
#pragma unroll
        for (int k = 0; k < 16; ++k) {
            float4 w = *(const float4*)(Wa + k * 16 + fo);
            yv[0] += a[k] * w.x; yv[1] += a[k] * w.y;
            yv[2] += a[k] * w.z; yv[3] += a[k] * w.w;
        }
#pragma unroll
        for (int j = 0; j < 4; ++j) yv[j] = tanhf(yv[j]);
    } else {
        int cnt = rowstart[node + 1] - rowstart[node];
        float inv = 1.0f / fmaxf((float)cnt, 1.0f);
#pragma unroll
        for (int k = 0; k < 16; ++k) a[k] *= inv;
#pragma unroll
        for (int j = 0; j < 4; ++j) yv[j] = ba[fo + j];
#pragma unroll
        for (int k = 0; k < 16; ++k) {
            float4 wa = *(const float4*)(Wa + k * 16 + fo);
            float4 wb = *(const float4*)(Wb + k * 16 + fo);
            yv[0] += a[k] * wa.x + s[k] * wb.x;
            yv[1] += a[k] * wa.y + s[k] * wb.y;
            yv[2] += a[k] * wa.z + s[k] * wb.z;
            yv[3] += a[k] * wa.w + s[k] * wb.w;
        }
        float sq = yv[0] * yv[0] + yv[1] * yv[1] + yv[2] * yv[2] + yv[3] * yv[3];
        sq += __shfl_xor(sq, 1);
        sq += __shfl_xor(sq, 2);
        float nrm = fmaxf(sqrtf(sq), 1e-12f);
#pragma unroll
        for (int j = 0; j < 4; ++j) yv[j] /= nrm;
        if (MODE == 1) {
#pragma unroll
            for (int j = 0; j < 4; ++j) yv[j] = tanhf(yv[j]);
        }
    }
    *(float4*)(hout + (size_t)node * 16 + fo) = make_float4(yv[0], yv[1], yv[2], yv[3]);
    if (hb16out) {
        uint2 pk = make_uint2(pack2(yv[0], yv[1]), pack2(yv[2], yv[3]));
        *(uint2*)(hb16out + (size_t)node * 8 + t4 * 2) = pk;
    }
}

// ---------------- Fused MLP v9: scalar-datapath W + software-prefetched W2 rows ----------------
// k-loop unrolled x2 with two statically-indexed uniform row buffers (wA/wB):
// next row's s_loads issue before current row's 32 FMAs -> hides scalar-L2 miss latency.
#define MLP_NODES 64
__global__ __launch_bounds__(256)
void k_mlp(const float* __restrict__ h3,
           const float* __restrict__ W1, const float* __restrict__ b1,
           const float* __restrict__ W2, const float* __restrict__ b2,
           const float* __restrict__ W3, const float* __restrict__ b3,
           float* __restrict__ out, int n) {
    __shared__ float t1T[128][65];
    __shared__ float hpart[MLP_NODES][5];

    int t = threadIdx.x;
    int w = t >> 6;
    int l = t & 63;
    int ow = __builtin_amdgcn_readfirstlane(w * 32);
    int node0 = blockIdx.x * MLP_NODES;
    int node = node0 + l;
    int nodec = min(node, n - 1);

    float acc[32];
    {
        float h[16];
        const float4* hp = (const float4*)(h3 + (size_t)nodec * 16);
#pragma unroll
        for (int q = 0; q < 4; ++q) {
            float4 v = hp[q];
            h[q * 4 + 0] = v.x; h[q * 4 + 1] = v.y; h[q * 4 + 2] = v.z; h[q * 4 + 3] = v.w;
        }
        const float* bp = b1 + ow;
#pragma unroll
        for (int j = 0; j < 32; ++j) acc[j] = bp[j];
#pragma unroll
        for (int k = 0; k < 16; ++k) {
            const float* wr = W1 + k * 128 + ow;
            float hk = h[k];
#pragma unroll
            for (int j = 0; j < 32; ++j) acc[j] += hk * wr[j];
        }
#pragma unroll
        for (int j = 0; j < 32; ++j) t1T[ow + j][l] = fmaxf(acc[j], 0.f);
    }
    __syncthreads();

    // layer 2 with depth-1 W2 row prefetch (static buffer indices)
    {
        const float* bp = b2 + ow;
#pragma unroll
        for (int j = 0; j < 32; ++j) acc[j] = bp[j];
    }
    float wA[32], wB[32];
    {
        const float* wr = W2 + ow;
#pragma unroll
        for (int j = 0; j < 32; ++j) wA[j] = wr[j];
    }
    for (int k = 0; k < 128; k += 2) {
        {
            const float* wr = W2 + (k + 1) * 128 + ow;
#pragma unroll
            for (int j = 0; j < 32; ++j) wB[j] = wr[j];
        }
        float tk = t1T[k][l];
#pragma unroll
        for (int j = 0; j < 32; ++j) acc[j] += tk * wA[j];
        if (k + 2 < 128) {
            const float* wr = W2 + (k + 2) * 128 + ow;
#pragma unroll
            for (int j = 0; j < 32; ++j) wA[j] = wr[j];
        }
        float tk2 = t1T[k + 1][l];
#pragma unroll
        for (int j = 0; j < 32; ++j) acc[j] += tk2 * wB[j];
    }

    float part = 0.f;
    {
        const float* wr = W3 + ow;
#pragma unroll
        for (int j = 0; j < 32; ++j) part += fmaxf(acc[j], 0.f) * wr[j];
    }
    hpart[l][w] = part;
    __syncthreads();
    if (w == 0 && node < n) {
        out[node] = hpart[l][0] + hpart[l][1] + hpart[l][2] + hpart[l][3] + b3[0];
    }
}

// ---------------- launch ----------------
extern "C" void kernel_launch(void* const* d_in, const int* in_sizes, int n_in,
                              void* d_out, int out_size, void* d_ws, size_t ws_size,
                              hipStream_t stream) {
    const float* x = (const float*)d_in[0];
    const int* ei = (const int*)d_in[1];
    const float* W_gcn = (const float*)d_in[2];
    const float* b_gcn = (const float*)d_in[3];
    const float* Wl1 = (const float*)d_in[4];
    const float* bl1 = (const float*)d_in[5];
    const float* Wr1 = (const float*)d_in[6];
    const float* Wl2 = (const float*)d_in[7];
    const float* bl2 = (const float*)d_in[8];
    const float* Wr2 = (const float*)d_in[9];
    const float* W1 = (const float*)d_in[10];
    const float* b1 = (const float*)d_in[11];
    const float* W2 = (const float*)d_in[12];
    const float* b2 = (const float*)d_in[13];
    const float* W3 = (const float*)d_in[14];
    const float* b3 = (const float*)d_in[15];

    const int N = in_sizes[0] / 16;
    const int E = in_sizes[1] / 2;
    const int NC = (N + 255) >> 8;
    const int chunk = (((E + NBLK - 1) / NBLK) + 3) & ~3;
    const int* src = ei;
    const int* dst = ei + E;

    char* w = (char*)d_ws;
    auto alloc = [&](size_t bytes) {
        void* p = (void*)w;
        w += (bytes + 255) & ~(size_t)255;
        return p;
    };
    int* gcur = (int*)alloc((size_t)NC * 4);
    int* totReal = (int*)alloc((size_t)NC * 4);
    int* rbase = (int*)alloc((size_t)NC * 4);
    int* rowstart = (int*)alloc((size_t)(N + 1) * 4);
    float* dinv = (float*)alloc((size_t)N * 4);
    int* bucketed = (int*)alloc((size_t)NC * BCAP * 4);
    int* csr = (int*)alloc((size_t)E * 4);
    float* xs = (float*)alloc((size_t)N * 16 * 4);
    float* agg = (float*)alloc((size_t)N * 16 * 4);
    float* h1 = (float*)alloc((size_t)N * 16 * 4);
    float* h2 = (float*)alloc((size_t)N * 16 * 4);
    float* h3 = (float*)alloc((size_t)N * 16 * 4);
    uint32* xsb = (uint32*)alloc((size_t)N * 8 * 4);
    uint32* h1b = (uint32*)alloc((size_t)N * 8 * 4);
    uint32* h2b = (uint32*)alloc((size_t)N * 8 * 4);

    k_init<<<(NC + 255) / 256, 256, 0, stream>>>(gcur, totReal, NC);
    k_fill<<<NBLK, 256, 0, stream>>>(src, dst, gcur, totReal, bucketed, E, NC, chunk);
    k_scanB<<<1, 512, 0, stream>>>(totReal, rbase, rowstart, E, NC, N);
    k_fine<<<NC, 512, 0, stream>>>(bucketed, gcur, rbase, csr, rowstart, dinv, N);

    int blk = 256;
    int ngrid = (N + blk - 1) / blk;
    long long agg_threads = (long long)N * 64;
    int agrid = (int)((agg_threads + blk - 1) / blk);
    int pgrid = (int)(((long long)N * 4 + blk - 1) / blk);

    k_prescale<<<ngrid, blk, 0, stream>>>(x, dinv, xs, xsb, N);

    // GCN
    k_agg<<<agrid, blk, 0, stream>>>(xsb, csr, rowstart, agg, N);
    k_post<0><<<pgrid, blk, 0, stream>>>(agg, xs, rowstart, dinv, W_gcn, b_gcn, W_gcn, h1, h1b, N);
    // SAGE 1
    k_agg<<<agrid, blk, 0, stream>>>(h1b, csr, rowstart, agg, N);
    k_post<1><<<pgrid, blk, 0, stream>>>(agg, h1, rowstart, dinv, Wl1, bl1, Wr1, h2, h2b, N);
    // SAGE 2
    k_agg<<<agrid, blk, 0, stream>>>(h2b, csr, rowstart, agg, N);
    k_post<2><<<pgrid, blk, 0, stream>>>(agg, h2, rowstart, dinv, Wl2, bl2, Wr2, h3, (uint32*)nullptr, N);

    int mgrid = (N + MLP_NODES - 1) / MLP_NODES;
    k_mlp<<<mgrid, blk, 0, stream>>>(h3, W1, b1, W2, b2, W3, b3, (float*)d_out, N);
}

// Round 20
// 309.477 us; speedup vs baseline: 1.2298x; 1.2298x over previous
//
#include <hip/hip_runtime.h>
#include <hip/hip_bf16.h>
#include <math.h>

#define NBLK 512
#define ROWS (NBLK / 256)
#define MAXNC 512     // supports N up to 131072 (256 nodes per coarse bucket)
#define STAGE_CAP 12512  // >= chunk = ceil(E/NBLK) 4-aligned (E=6.4M -> 12500)

typedef float vfloat4 __attribute__((ext_vector_type(4)));
typedef float f32x4 __attribute__((ext_vector_type(4)));
typedef short bf16x8v __attribute__((ext_vector_type(8)));
typedef unsigned int uint32;

__device__ __forceinline__ float bf_lo(uint32 u) { return __uint_as_float(u << 16); }
__device__ __forceinline__ float bf_hi(uint32 u) { return __uint_as_float(u & 0xFFFF0000u); }
__device__ __forceinline__ uint32 f2b(float f) {  // fp32 -> bf16 bits, RNE
    uint32 u = __float_as_uint(f);
    return (u + 0x7FFFu + ((u >> 16) & 1u)) >> 16;
}
__device__ __forceinline__ uint32 pack2(float a, float b) { return f2b(a) | (f2b(b) << 16); }
__device__ __forceinline__ bf16x8v as_bf(uint4 u) {
    union { uint4 a; bf16x8v b; } v; v.a = u; return v.b;
}

// ---------------- pass A: coarse histogram per block chunk (int4 loads) ----------------
__global__ void k_hist(const int* __restrict__ dst, int* __restrict__ hist,
                       int nE, int nc, int chunk) {
    __shared__ int ch[MAXNC];
    int b = blockIdx.x, t = threadIdx.x;
    for (int i = t; i < nc; i += 256) ch[i] = 0;
    __syncthreads();
    int c0 = b * chunk, c1 = min(nE, c0 + chunk);
    if (c1 > c0) {
        int nv = (c1 - c0) >> 2;
        const int4* d4 = (const int4*)(dst + c0);
        for (int i = t; i < nv; i += 256) {
            int4 dd = d4[i];
            atomicAdd(&ch[dd.x >> 8], 1);
            atomicAdd(&ch[dd.y >> 8], 1);
            atomicAdd(&ch[dd.z >> 8], 1);
            atomicAdd(&ch[dd.w >> 8], 1);
        }
        int rem = (c1 - c0) & 3;
        if (t < rem) atomicAdd(&ch[dst[c0 + (nv << 2) + t] >> 8], 1);
    }
    __syncthreads();
    for (int i = t; i < nc; i += 256) hist[b * nc + i] = ch[i];
}

// ---------------- pass B1: per-bucket scan -> padded offT, padded & real totals ----------------
__global__ void k_scanA(const int* __restrict__ hist, int* __restrict__ offT,
                        int* __restrict__ totPad, int* __restrict__ totReal, int nc) {
    __shared__ int sums[256];
    __shared__ int red[256];
    int c = blockIdx.x, t = threadIdx.x;
    int v[ROWS], p[ROWS];
    int s = 0, sr = 0;
#pragma unroll
    for (int j = 0; j < ROWS; ++j) {
        v[j] = hist[(size_t)(t * ROWS + j) * nc + c];
        p[j] = (v[j] + 15) & ~15;
        s += p[j];
        sr += v[j];
    }
    sums[t] = s;
    red[t] = sr;
    __syncthreads();
    for (int d = 1; d < 256; d <<= 1) {
        int x = (t >= d) ? sums[t - d] : 0;
        __syncthreads();
        sums[t] += x;
        __syncthreads();
    }
    int run = sums[t] - s;
#pragma unroll
    for (int j = 0; j < ROWS; ++j) {
        offT[(size_t)c * NBLK + t * ROWS + j] = run;
        run += p[j];
    }
    if (t == 255) totPad[c] = sums[255];
    for (int d = 128; d > 0; d >>= 1) {
        if (t < d) red[t] += red[t + d];
        __syncthreads();
    }
    if (t == 0) totReal[c] = red[0];
}

// ---------------- pass B2: scan totals -> cbase (padded) and rbase (real) ----------------
__global__ void k_scanB(const int* __restrict__ totPad, const int* __restrict__ totReal,
                        int* __restrict__ cbase, int* __restrict__ rbase,
                        int* __restrict__ rowstart, int nE, int nc, int n) {
    __shared__ int sp[512];
    __shared__ int sr[512];
    int t = threadIdx.x;
    int vp = (t < nc) ? totPad[t] : 0;
    int vr = (t < nc) ? totReal[t] : 0;
    sp[t] = vp; sr[t] = vr;
    __syncthreads();
    for (int d = 1; d < 512; d <<= 1) {
        int xp = (t >= d) ? sp[t - d] : 0;
        int xr = (t >= d) ? sr[t - d] : 0;
        __syncthreads();
        sp[t] += xp; sr[t] += xr;
        __syncthreads();
    }
    if (t < nc) { cbase[t] = sp[t] - vp; rbase[t] = sr[t] - vr; }
    if (t == nc - 1) cbase[nc] = sp[t];
    if (t == 0) rowstart[n] = nE;
}

// ---------------- pass C: LDS-staged partition + full-line flush ----------------
__global__ __launch_bounds__(256, 2)
void k_fill(const int* __restrict__ src, const int* __restrict__ dst,
            const int* __restrict__ hist, const int* __restrict__ offT,
            const int* __restrict__ cbase,
            int* __restrict__ bucketed, int nE, int nc, int chunk) {
    __shared__ int stage[STAGE_CAP];
    __shared__ int sc[256];
    __shared__ int lbeg[MAXNC];
    __shared__ int lcur[MAXNC];
    int b = blockIdx.x, t = threadIdx.x;

    int v0 = (2 * t < nc) ? hist[(size_t)b * nc + 2 * t] : 0;
    int v1 = (2 * t + 1 < nc) ? hist[(size_t)b * nc + 2 * t + 1] : 0;
    int s = v0 + v1;
    sc[t] = s;
    __syncthreads();
    for (int d = 1; d < 256; d <<= 1) {
        int x = (t >= d) ? sc[t - d] : 0;
        __syncthreads();
        sc[t] += x;
        __syncthreads();
    }
    int excl = sc[t] - s;
    if (2 * t < nc) { lbeg[2 * t] = excl; lcur[2 * t] = excl; }
    if (2 * t + 1 < nc) { lbeg[2 * t + 1] = excl + v0; lcur[2 * t + 1] = excl + v0; }
    __syncthreads();

    int c0 = b * chunk, c1 = min(nE, c0 + chunk);
    if (c1 > c0) {
        int nv = (c1 - c0) >> 2;
        const int4* d4 = (const int4*)(dst + c0);
        const int4* s4 = (const int4*)(src + c0);
        for (int i = t; i < nv; i += 256) {
            int4 dd = d4[i];
            int4 ss = s4[i];
            int pos;
            pos = atomicAdd(&lcur[dd.x >> 8], 1); stage[pos] = ss.x | ((dd.x & 255) << 17);
            pos = atomicAdd(&lcur[dd.y >> 8], 1); stage[pos] = ss.y | ((dd.y & 255) << 17);
            pos = atomicAdd(&lcur[dd.z >> 8], 1); stage[pos] = ss.z | ((dd.z & 255) << 17);
            pos = atomicAdd(&lcur[dd.w >> 8], 1); stage[pos] = ss.w | ((dd.w & 255) << 17);
        }
        int rem = (c1 - c0) & 3;
        if (t < rem) {
            int e = c0 + (nv << 2) + t;
            int d = dst[e];
            int pos = atomicAdd(&lcur[d >> 8], 1);
            stage[pos] = src[e] | ((d & 255) << 17);
        }
    }
    __syncthreads();

    for (int c = t; c < nc; c += 256) {
        int lo = lbeg[c];
        int cnt = lcur[c] - lo;
        int g = cbase[c] + offT[(size_t)c * NBLK + b];
        int padded = (cnt + 15) & ~15;
        for (int i = 0; i < padded; i += 4) {
            int4 v;
            v.x = (i + 0 < cnt) ? stage[lo + i + 0] : -1;
            v.y = (i + 1 < cnt) ? stage[lo + i + 1] : -1;
            v.z = (i + 2 < cnt) ? stage[lo + i + 2] : -1;
            v.w = (i + 3 < cnt) ? stage[lo + i + 3] : -1;
            *(int4*)(bucketed + g + i) = v;
        }
    }
}

// ---------------- pass D: within-bucket sort to compact per-node CSR ----------------
__global__ void k_fine(const int* __restrict__ bucketed, const int* __restrict__ cbase,
                       const int* __restrict__ rbase,
                       int* __restrict__ csr, int* __restrict__ rowstart,
                       float* __restrict__ dinv, int n) {
    __shared__ int cnt[256];
    __shared__ int lrs[512];
    __shared__ int cur[256];
    int cb = blockIdx.x, t = threadIdx.x;  // 512 threads
    int e0 = cbase[cb], e1 = cbase[cb + 1];
    int r0 = rbase[cb];
    if (t < 256) cnt[t] = 0;
    __syncthreads();
    int nv = (e1 - e0) >> 2;
    const int4* b4 = (const int4*)(bucketed + e0);
    for (int i = t; i < nv; i += 512) {
        int4 en = b4[i];
        if (en.x >= 0) atomicAdd(&cnt[(en.x >> 17) & 255], 1);
        if (en.y >= 0) atomicAdd(&cnt[(en.y >> 17) & 255], 1);
        if (en.z >= 0) atomicAdd(&cnt[(en.z >> 17) & 255], 1);
        if (en.w >= 0) atomicAdd(&cnt[(en.w >> 17) & 255], 1);
    }
    __syncthreads();
    int my = (t < 256) ? cnt[t] : 0;
    lrs[t] = my;
    __syncthreads();
    for (int d = 1; d < 512; d <<= 1) {
        int x = (t >= d) ? lrs[t - d] : 0;
        __syncthreads();
        lrs[t] += x;
        __syncthreads();
    }
    if (t < 256) {
        int excl = lrs[t] - my;
        int node = cb * 256 + t;
        if (node < n) {
            rowstart[node] = r0 + excl;
            dinv[node] = rsqrtf((float)(my + 1));
        }
        cur[t] = r0 + excl;
    }
    __syncthreads();
    for (int i = t; i < nv; i += 512) {
        int4 en = b4[i];
        int pos;
        if (en.x >= 0) { pos = atomicAdd(&cur[(en.x >> 17) & 255], 1); csr[pos] = en.x & 0x1FFFF; }
        if (en.y >= 0) { pos = atomicAdd(&cur[(en.y >> 17) & 255], 1); csr[pos] = en.y & 0x1FFFF; }
        if (en.z >= 0) { pos = atomicAdd(&cur[(en.z >> 17) & 255], 1); csr[pos] = en.z & 0x1FFFF; }
        if (en.w >= 0) { pos = atomicAdd(&cur[(en.w >> 17) & 255], 1); csr[pos] = en.w & 0x1FFFF; }
    }
}

// ---------------- prescale: xs = dinv * x (fp32) + bf16 shadow ----------------
__global__ void k_prescale(const float* __restrict__ x, const float* __restrict__ dinv,
                           float* __restrict__ xs, uint32* __restrict__ xsb, int n) {
    int i = blockIdx.x * blockDim.x + threadIdx.x;
    if (i >= n) return;
    float di = dinv[i];
    const float4* xp = (const float4*)(x + (size_t)i * 16);
    float4* op = (float4*)(xs + (size_t)i * 16);
    uint32 pk[8];
#pragma unroll
    for (int q = 0; q < 4; ++q) {
        float4 v = xp[q];
        v.x *= di; v.y *= di; v.z *= di; v.w *= di;
        op[q] = v;
        pk[q * 2 + 0] = pack2(v.x, v.y);
        pk[q * 2 + 1] = pack2(v.z, v.w);
    }
    uint4* bp = (uint4*)(xsb + (size_t)i * 8);
    bp[0] = make_uint4(pk[0], pk[1], pk[2], pk[3]);
    bp[1] = make_uint4(pk[4], pk[5], pk[6], pk[7]);
}

// ---------------- agg: wave/node, 16 slots x 4 lanes, batch-4 bf16 gathers ----------------
__global__ void k_agg(const uint32* __restrict__ hb16, const int* __restrict__ csr,
                      const int* __restrict__ rowstart, float* __restrict__ agg, int n) {
    int wid = (blockIdx.x * blockDim.x + threadIdx.x) >> 6;
    if (wid >= n) return;
    int lane = threadIdx.x & 63;
    int q = lane >> 2;   // edge slot 0..15
    int c = lane & 3;    // feature quad
    int r0 = rowstart[wid], r1 = rowstart[wid + 1];
    int cnt = r1 - r0;
    const int* p = csr + r0 + q;
    int my = (cnt > q) ? ((cnt - q + 15) >> 4) : 0;
    const uint2* hb = (const uint2*)hb16;

    float av[4] = {0.f, 0.f, 0.f, 0.f};
    int t = 0;
    for (; t + 4 <= my; t += 4) {
        int s0 = __builtin_nontemporal_load(p + (t + 0) * 16);
        int s1 = __builtin_nontemporal_load(p + (t + 1) * 16);
        int s2 = __builtin_nontemporal_load(p + (t + 2) * 16);
        int s3 = __builtin_nontemporal_load(p + (t + 3) * 16);
        uint2 w0 = hb[(size_t)s0 * 4 + c];
        uint2 w1 = hb[(size_t)s1 * 4 + c];
        uint2 w2 = hb[(size_t)s2 * 4 + c];
        uint2 w3 = hb[(size_t)s3 * 4 + c];
        av[0] += (bf_lo(w0.x) + bf_lo(w1.x)) + (bf_lo(w2.x) + bf_lo(w3.x));
        av[1] += (bf_hi(w0.x) + bf_hi(w1.x)) + (bf_hi(w2.x) + bf_hi(w3.x));
        av[2] += (bf_lo(w0.y) + bf_lo(w1.y)) + (bf_lo(w2.y) + bf_lo(w3.y));
        av[3] += (bf_hi(w0.y) + bf_hi(w1.y)) + (bf_hi(w2.y) + bf_hi(w3.y));
    }
    if (t + 2 <= my) {
        int s0 = __builtin_nontemporal_load(p + (t + 0) * 16);
        int s1 = __builtin_nontemporal_load(p + (t + 1) * 16);
        uint2 w0 = hb[(size_t)s0 * 4 + c];
        uint2 w1 = hb[(size_t)s1 * 4 + c];
        av[0] += bf_lo(w0.x) + bf_lo(w1.x);
        av[1] += bf_hi(w0.x) + bf_hi(w1.x);
        av[2] += bf_lo(w0.y) + bf_lo(w1.y);
        av[3] += bf_hi(w0.y) + bf_hi(w1.y);
        t += 2;
    }
    if (t < my) {
        int s0 = __builtin_nontemporal_load(p + t * 16);
        uint2 w0 = hb[(size_t)s0 * 4 + c];
        av[0] += bf_lo(w0.x); av[1] += bf_hi(w0.x);
        av[2] += bf_lo(w0.y); av[3] += bf_hi(w0.y);
    }
#pragma unroll
    for (int m = 4; m <= 32; m <<= 1) {
#pragma unroll
        for (int j = 0; j < 4; ++j) av[j] += __shfl_xor(av[j], m);
    }
    if (q == 0) {
        vfloat4 o = {av[0], av[1], av[2], av[3]};
        __builtin_nontemporal_store(o, (vfloat4*)(agg + (size_t)wid * 16 + c * 4));
    }
}

// ---------------- post: 4 threads/node, GEMM + activation; writes fp32 + bf16 shadow ----------------
template <int MODE>
__global__ void k_post(const float* __restrict__ agg, const float* __restrict__ hin,
                       const int* __restrict__ rowstart, const float* __restrict__ dinv,
                       const float* __restrict__ Wa, const float* __restrict__ ba,
                       const float* __restrict__ Wb,
                       float* __restrict__ hout, uint32* __restrict__ hb16out, int n) {
    int idx = blockIdx.x * blockDim.x + threadIdx.x;
    int node = idx >> 2;
    if (node >= n) return;
    int t4 = idx & 3;
    int lane = threadIdx.x & 63;
    int lbase = lane & 60;

    float4 av = *(const float4*)(agg + (size_t)node * 16 + t4 * 4);
    float4 sv = *(const float4*)(hin + (size_t)node * 16 + t4 * 4);

    float a[16], s[16];
#pragma unroll
    for (int g = 0; g < 4; ++g) {
        a[g * 4 + 0] = __shfl(av.x, lbase + g);
        a[g * 4 + 1] = __shfl(av.y, lbase + g);
        a[g * 4 + 2] = __shfl(av.z, lbase + g);
        a[g * 4 + 3] = __shfl(av.w, lbase + g);
        s[g * 4 + 0] = __shfl(sv.x, lbase + g);
        s[g * 4 + 1] = __shfl(sv.y, lbase + g);
        s[g * 4 + 2] = __shfl(sv.z, lbase + g);
        s[g * 4 + 3] = __shfl(sv.w, lbase + g);
    }

    int fo = t4 * 4;
    float yv[4];
    if (MODE == 0) {
        float di = dinv[node];
#pragma unroll
        for (int k = 0; k < 16; ++k) a[k] = di * (a[k] + s[k]);
#pragma unroll
        for (int j = 0; j < 4; ++j) yv[j] = ba[fo + j];
#pragma unroll
        for (int k = 0; k < 16; ++k) {
            float4 w = *(const float4*)(Wa + k * 16 + fo);
            yv[0] += a[k] * w.x; yv[1] += a[k] * w.y;
            yv[2] += a[k] * w.z; yv[3] += a[k] * w.w;
        }
#pragma unroll
        for (int j = 0; j < 4; ++j) yv[j] = tanhf(yv[j]);
    } else {
        int cnt = rowstart[node + 1] - rowstart[node];
        float inv = 1.0f / fmaxf((float)cnt, 1.0f);
#pragma unroll
        for (int k = 0; k < 16; ++k) a[k] *= inv;
#pragma unroll
        for (int j = 0; j < 4; ++j) yv[j] = ba[fo + j];
#pragma unroll
        for (int k = 0; k < 16; ++k) {
            float4 wa = *(const float4*)(Wa + k * 16 + fo);
            float4 wb = *(const float4*)(Wb + k * 16 + fo);
            yv[0] += a[k] * wa.x + s[k] * wb.x;
            yv[1] += a[k] * wa.y + s[k] * wb.y;
            yv[2] += a[k] * wa.z + s[k] * wb.z;
            yv[3] += a[k] * wa.w + s[k] * wb.w;
        }
        float sq = yv[0] * yv[0] + yv[1] * yv[1] + yv[2] * yv[2] + yv[3] * yv[3];
        sq += __shfl_xor(sq, 1);
        sq += __shfl_xor(sq, 2);
        float nrm = fmaxf(sqrtf(sq), 1e-12f);
#pragma unroll
        for (int j = 0; j < 4; ++j) yv[j] /= nrm;
        if (MODE == 1) {
#pragma unroll
            for (int j = 0; j < 4; ++j) yv[j] = tanhf(yv[j]);
        }
    }
    *(float4*)(hout + (size_t)node * 16 + fo) = make_float4(yv[0], yv[1], yv[2], yv[3]);
    if (hb16out) {
        uint2 pk = make_uint2(pack2(yv[0], yv[1]), pack2(yv[2], yv[3]));
        *(uint2*)(hb16out + (size_t)node * 8 + t4 * 2) = pk;
    }
}

// ---------------- W2 pack: [k][out] fp32 -> [out][k/2] bf16-pair hi + lo residual ----------------
__global__ void k_wpack(const float* __restrict__ W2, uint32* __restrict__ hi,
                        uint32* __restrict__ lo) {
    int u = blockIdx.x * blockDim.x + threadIdx.x;  // 8192 = 128 outs x 64 k-pairs
    if (u >= 8192) return;
    int outc = u >> 6;
    int ui = u & 63;
    float a = W2[(size_t)(2 * ui) * 128 + outc];
    float b = W2[(size_t)(2 * ui + 1) * 128 + outc];
    uint32 h = pack2(a, b);
    float ra = a - bf_lo(h);
    float rb = b - bf_hi(h);
    hi[u] = h;
    lo[u] = pack2(ra, rb);
}

// ---------------- Fused MLP v10: layer1 VALU + layer2 MFMA bf16 hi/lo split ----------------
// Layer 2 = [16 nodes x 128] @ [128 x 16 outs] tiles via mfma_f32_16x16x32_bf16.
// hi/lo split: t1*W2 ~= t1h*W2h + t1h*W2l + t1l*W2h (lo*lo ~ 2^-16 rel, dropped).
// Fragment maps (m89/m91-verified family): a[j]=A[l&15][(l>>4)*8+j],
// b[j]=B[(l>>4)*8+j][l&15], d[j]=D[(l>>4)*4+j][l&15].
#define MLP_NODES 64
__global__ __launch_bounds__(256)
void k_mlp(const float* __restrict__ h3,
           const float* __restrict__ W1, const float* __restrict__ b1,
           const uint32* __restrict__ W2h, const uint32* __restrict__ W2l,
           const float* __restrict__ b2,
           const float* __restrict__ W3, const float* __restrict__ b3,
           float* __restrict__ out, int n) {
    __shared__ __align__(16) uint32 t1h[64][68];  // [node][k/2] bf16 pairs (hi)
    __shared__ __align__(16) uint32 t1l[64][68];  // residual (lo)
    __shared__ float hpart[MLP_NODES][5];

    int t = threadIdx.x;
    int w = t >> 6;
    int l = t & 63;
    int ow = __builtin_amdgcn_readfirstlane(w * 32);
    int node0 = blockIdx.x * MLP_NODES;
    int node = node0 + l;
    int nodec = min(node, n - 1);
    int cl = l & 15, kg = l >> 4;

    // ---- layer 1: VALU, scalar-datapath W1 (v7 structure) ----
    {
        float h[16];
        const float4* hp = (const float4*)(h3 + (size_t)nodec * 16);
#pragma unroll
        for (int q = 0; q < 4; ++q) {
            float4 v = hp[q];
            h[q * 4 + 0] = v.x; h[q * 4 + 1] = v.y; h[q * 4 + 2] = v.z; h[q * 4 + 3] = v.w;
        }
        float acc[32];
        const float* bp = b1 + ow;  // uniform -> s_load
#pragma unroll
        for (int j = 0; j < 32; ++j) acc[j] = bp[j];
#pragma unroll
        for (int k = 0; k < 16; ++k) {
            const float* wr = W1 + k * 128 + ow;  // uniform -> s_load
            float hk = h[k];
#pragma unroll
            for (int j = 0; j < 32; ++j) acc[j] += hk * wr[j];
        }
        // relu + hi/lo bf16 pack into LDS
#pragma unroll
        for (int j = 0; j < 32; j += 2) {
            float a0 = fmaxf(acc[j], 0.f), a1 = fmaxf(acc[j + 1], 0.f);
            uint32 hi = pack2(a0, a1);
            float r0 = a0 - bf_lo(hi);
            float r1 = a1 - bf_hi(hi);
            int ui = (ow + j) >> 1;
            t1h[l][ui] = hi;
            t1l[l][ui] = pack2(r0, r1);
        }
    }

    // ---- B fragments for this wave's 32 outs (hi/lo), from packed W2 ----
    uint4 bh0[4], bl0[4], bh1[4], bl1[4];
    {
        int c0 = ow + cl, c1 = ow + 16 + cl;
        const uint4* ph0 = (const uint4*)(W2h + (size_t)c0 * 64);
        const uint4* pl0 = (const uint4*)(W2l + (size_t)c0 * 64);
        const uint4* ph1 = (const uint4*)(W2h + (size_t)c1 * 64);
        const uint4* pl1 = (const uint4*)(W2l + (size_t)c1 * 64);
#pragma unroll
        for (int ks = 0; ks < 4; ++ks) {
            bh0[ks] = ph0[ks * 4 + kg];
            bl0[ks] = pl0[ks * 4 + kg];
            bh1[ks] = ph1[ks * 4 + kg];
            bl1[ks] = pl1[ks * 4 + kg];
        }
    }
    float b2v0 = b2[ow + cl], b2v1 = b2[ow + 16 + cl];
    float w3v0 = W3[ow + cl], w3v1 = W3[ow + 16 + cl];
    __syncthreads();

    // ---- layer 2 MFMA + layer 3 reduce, per 16-node group ----
    for (int ng = 0; ng < 4; ++ng) {
        int an = ng * 16 + cl;
        const uint4* pah = (const uint4*)(&t1h[an][0]);
        const uint4* pal = (const uint4*)(&t1l[an][0]);
        uint4 ahu[4], alu[4];
#pragma unroll
        for (int ks = 0; ks < 4; ++ks) {
            ahu[ks] = pah[ks * 4 + kg];
            alu[ks] = pal[ks * 4 + kg];
        }
        f32x4 acc0 = {b2v0, b2v0, b2v0, b2v0};
        f32x4 acc1 = {b2v1, b2v1, b2v1, b2v1};
#pragma unroll
        for (int ks = 0; ks < 4; ++ks) {
            bf16x8v a_h = as_bf(ahu[ks]);
            bf16x8v a_l = as_bf(alu[ks]);
            acc0 = __builtin_amdgcn_mfma_f32_16x16x32_bf16(a_h, as_bf(bh0[ks]), acc0, 0, 0, 0);
            acc0 = __builtin_amdgcn_mfma_f32_16x16x32_bf16(a_h, as_bf(bl0[ks]), acc0, 0, 0, 0);
            acc0 = __builtin_amdgcn_mfma_f32_16x16x32_bf16(a_l, as_bf(bh0[ks]), acc0, 0, 0, 0);
            acc1 = __builtin_amdgcn_mfma_f32_16x16x32_bf16(a_h, as_bf(bh1[ks]), acc1, 0, 0, 0);
            acc1 = __builtin_amdgcn_mfma_f32_16x16x32_bf16(a_h, as_bf(bl1[ks]), acc1, 0, 0, 0);
            acc1 = __builtin_amdgcn_mfma_f32_16x16x32_bf16(a_l, as_bf(bh1[ks]), acc1, 0, 0, 0);
        }
        // layer 3: relu(acc) . W3 over this wave's 32 cols; reduce across 16 col-lanes
        float pj[4];
#pragma unroll
        for (int j = 0; j < 4; ++j)
            pj[j] = fmaxf(acc0[j], 0.f) * w3v0 + fmaxf(acc1[j], 0.f) * w3v1;
#pragma unroll
        for (int m = 1; m <= 8; m <<= 1) {
#pragma unroll
            for (int j = 0; j < 4; ++j) pj[j] += __shfl_xor(pj[j], m);
        }
        if (cl == 0) {
#pragma unroll
            for (int j = 0; j < 4; ++j) hpart[ng * 16 + kg * 4 + j][w] = pj[j];
        }
    }
    __syncthreads();
    if (w == 0 && node < n) {
        out[node] = hpart[l][0] + hpart[l][1] + hpart[l][2] + hpart[l][3] + b3[0];
    }
}

// ---------------- launch ----------------
extern "C" void kernel_launch(void* const* d_in, const int* in_sizes, int n_in,
                              void* d_out, int out_size, void* d_ws, size_t ws_size,
                              hipStream_t stream) {
    const float* x = (const float*)d_in[0];
    const int* ei = (const int*)d_in[1];
    const float* W_gcn = (const float*)d_in[2];
    const float* b_gcn = (const float*)d_in[3];
    const float* Wl1 = (const float*)d_in[4];
    const float* bl1 = (const float*)d_in[5];
    const float* Wr1 = (const float*)d_in[6];
    const float* Wl2 = (const float*)d_in[7];
    const float* bl2 = (const float*)d_in[8];
    const float* Wr2 = (const float*)d_in[9];
    const float* W1 = (const float*)d_in[10];
    const float* b1 = (const float*)d_in[11];
    const float* W2 = (const float*)d_in[12];
    const float* b2 = (const float*)d_in[13];
    const float* W3 = (const float*)d_in[14];
    const float* b3 = (const float*)d_in[15];

    const int N = in_sizes[0] / 16;
    const int E = in_sizes[1] / 2;
    const int NC = (N + 255) >> 8;
    const int chunk = (((E + NBLK - 1) / NBLK) + 3) & ~3;
    const int* src = ei;
    const int* dst = ei + E;

    char* w = (char*)d_ws;
    auto alloc = [&](size_t bytes) {
        void* p = (void*)w;
        w += (bytes + 255) & ~(size_t)255;
        return p;
    };
    int* hist = (int*)alloc((size_t)NBLK * NC * 4);
    int* offT = (int*)alloc((size_t)NBLK * NC * 4);
    int* totPad = (int*)alloc((size_t)NC * 4);
    int* totReal = (int*)alloc((size_t)NC * 4);
    int* cbase = (int*)alloc((size_t)(NC + 1) * 4);
    int* rbase = (int*)alloc((size_t)NC * 4);
    int* rowstart = (int*)alloc((size_t)(N + 1) * 4);
    float* dinv = (float*)alloc((size_t)N * 4);
    int* bucketed = (int*)alloc(((size_t)E + (size_t)NBLK * NC * 16) * 4);
    int* csr = (int*)alloc((size_t)E * 4);
    float* xs = (float*)alloc((size_t)N * 16 * 4);
    float* agg = (float*)alloc((size_t)N * 16 * 4);
    float* h1 = (float*)alloc((size_t)N * 16 * 4);
    float* h2 = (float*)alloc((size_t)N * 16 * 4);
    float* h3 = (float*)alloc((size_t)N * 16 * 4);
    uint32* xsb = (uint32*)alloc((size_t)N * 8 * 4);
    uint32* h1b = (uint32*)alloc((size_t)N * 8 * 4);
    uint32* h2b = (uint32*)alloc((size_t)N * 8 * 4);
    uint32* w2h = (uint32*)alloc((size_t)128 * 64 * 4);
    uint32* w2l = (uint32*)alloc((size_t)128 * 64 * 4);

    k_wpack<<<32, 256, 0, stream>>>(W2, w2h, w2l);
    k_hist<<<NBLK, 256, 0, stream>>>(dst, hist, E, NC, chunk);
    k_scanA<<<NC, 256, 0, stream>>>(hist, offT, totPad, totReal, NC);
    k_scanB<<<1, 512, 0, stream>>>(totPad, totReal, cbase, rbase, rowstart, E, NC, N);
    k_fill<<<NBLK, 256, 0, stream>>>(src, dst, hist, offT, cbase, bucketed, E, NC, chunk);
    k_fine<<<NC, 512, 0, stream>>>(bucketed, cbase, rbase, csr, rowstart, dinv, N);

    int blk = 256;
    int ngrid = (N + blk - 1) / blk;
    long long agg_threads = (long long)N * 64;
    int agrid = (int)((agg_threads + blk - 1) / blk);
    int pgrid = (int)(((long long)N * 4 + blk - 1) / blk);

    k_prescale<<<ngrid, blk, 0, stream>>>(x, dinv, xs, xsb, N);

    // GCN
    k_agg<<<agrid, blk, 0, stream>>>(xsb, csr, rowstart, agg, N);
    k_post<0><<<pgrid, blk, 0, stream>>>(agg, xs, rowstart, dinv, W_gcn, b_gcn, W_gcn, h1, h1b, N);
    // SAGE 1
    k_agg<<<agrid, blk, 0, stream>>>(h1b, csr, rowstart, agg, N);
    k_post<1><<<pgrid, blk, 0, stream>>>(agg, h1, rowstart, dinv, Wl1, bl1, Wr1, h2, h2b, N);
    // SAGE 2
    k_agg<<<agrid, blk, 0, stream>>>(h2b, csr, rowstart, agg, N);
    k_post<2><<<pgrid, blk, 0, stream>>>(agg, h2, rowstart, dinv, Wl2, bl2, Wr2, h3, (uint32*)nullptr, N);

    int mgrid = (N + MLP_NODES - 1) / MLP_NODES;
    k_mlp<<<mgrid, blk, 0, stream>>>(h3, W1, b1, w2h, w2l, b2, W3, b3, (float*)d_out, N);
}

// Round 21
// 307.449 us; speedup vs baseline: 1.2380x; 1.0066x over previous
//
#include <hip/hip_runtime.h>
#include <hip/hip_bf16.h>
#include <math.h>

#define NBLK 512
#define ROWS (NBLK / 256)
#define MAXNC 512     // supports N up to 131072 (256 nodes per coarse bucket)
#define STAGE_CAP 12512  // >= chunk = ceil(E/NBLK) 4-aligned (E=6.4M -> 12500)

typedef float vfloat4 __attribute__((ext_vector_type(4)));
typedef float f32x4 __attribute__((ext_vector_type(4)));
typedef short bf16x8v __attribute__((ext_vector_type(8)));
typedef unsigned int uint32;

__device__ __forceinline__ float bf_lo(uint32 u) { return __uint_as_float(u << 16); }
__device__ __forceinline__ float bf_hi(uint32 u) { return __uint_as_float(u & 0xFFFF0000u); }
__device__ __forceinline__ uint32 f2b(float f) {  // fp32 -> bf16 bits, RNE
    uint32 u = __float_as_uint(f);
    return (u + 0x7FFFu + ((u >> 16) & 1u)) >> 16;
}
__device__ __forceinline__ uint32 pack2(float a, float b) { return f2b(a) | (f2b(b) << 16); }
__device__ __forceinline__ bf16x8v as_bf(uint4 u) {
    union { uint4 a; bf16x8v b; } v; v.a = u; return v.b;
}

// ---------------- pass A: coarse histogram per block chunk (int4 loads) ----------------
__global__ void k_hist(const int* __restrict__ dst, int* __restrict__ hist,
                       int nE, int nc, int chunk) {
    __shared__ int ch[MAXNC];
    int b = blockIdx.x, t = threadIdx.x;
    for (int i = t; i < nc; i += 256) ch[i] = 0;
    __syncthreads();
    int c0 = b * chunk, c1 = min(nE, c0 + chunk);
    if (c1 > c0) {
        int nv = (c1 - c0) >> 2;
        const int4* d4 = (const int4*)(dst + c0);
        for (int i = t; i < nv; i += 256) {
            int4 dd = d4[i];
            atomicAdd(&ch[dd.x >> 8], 1);
            atomicAdd(&ch[dd.y >> 8], 1);
            atomicAdd(&ch[dd.z >> 8], 1);
            atomicAdd(&ch[dd.w >> 8], 1);
        }
        int rem = (c1 - c0) & 3;
        if (t < rem) atomicAdd(&ch[dst[c0 + (nv << 2) + t] >> 8], 1);
    }
    __syncthreads();
    for (int i = t; i < nc; i += 256) hist[b * nc + i] = ch[i];
}

// ---------------- pass B1: per-bucket scan -> padded offT, padded & real totals ----------------
__global__ void k_scanA(const int* __restrict__ hist, int* __restrict__ offT,
                        int* __restrict__ totPad, int* __restrict__ totReal, int nc) {
    __shared__ int sums[256];
    __shared__ int red[256];
    int c = blockIdx.x, t = threadIdx.x;
    int v[ROWS], p[ROWS];
    int s = 0, sr = 0;
#pragma unroll
    for (int j = 0; j < ROWS; ++j) {
        v[j] = hist[(size_t)(t * ROWS + j) * nc + c];
        p[j] = (v[j] + 15) & ~15;
        s += p[j];
        sr += v[j];
    }
    sums[t] = s;
    red[t] = sr;
    __syncthreads();
    for (int d = 1; d < 256; d <<= 1) {
        int x = (t >= d) ? sums[t - d] : 0;
        __syncthreads();
        sums[t] += x;
        __syncthreads();
    }
    int run = sums[t] - s;
#pragma unroll
    for (int j = 0; j < ROWS; ++j) {
        offT[(size_t)c * NBLK + t * ROWS + j] = run;
        run += p[j];
    }
    if (t == 255) totPad[c] = sums[255];
    for (int d = 128; d > 0; d >>= 1) {
        if (t < d) red[t] += red[t + d];
        __syncthreads();
    }
    if (t == 0) totReal[c] = red[0];
}

// ---------------- pass B2: scan totals -> cbase (padded) and rbase (real) ----------------
__global__ void k_scanB(const int* __restrict__ totPad, const int* __restrict__ totReal,
                        int* __restrict__ cbase, int* __restrict__ rbase,
                        int* __restrict__ rowstart, int nE, int nc, int n) {
    __shared__ int sp[512];
    __shared__ int sr[512];
    int t = threadIdx.x;
    int vp = (t < nc) ? totPad[t] : 0;
    int vr = (t < nc) ? totReal[t] : 0;
    sp[t] = vp; sr[t] = vr;
    __syncthreads();
    for (int d = 1; d < 512; d <<= 1) {
        int xp = (t >= d) ? sp[t - d] : 0;
        int xr = (t >= d) ? sr[t - d] : 0;
        __syncthreads();
        sp[t] += xp; sr[t] += xr;
        __syncthreads();
    }
    if (t < nc) { cbase[t] = sp[t] - vp; rbase[t] = sr[t] - vr; }
    if (t == nc - 1) cbase[nc] = sp[t];
    if (t == 0) rowstart[n] = nE;
}

// ---------------- pass C: LDS-staged partition + full-line flush ----------------
__global__ __launch_bounds__(256, 2)
void k_fill(const int* __restrict__ src, const int* __restrict__ dst,
            const int* __restrict__ hist, const int* __restrict__ offT,
            const int* __restrict__ cbase,
            int* __restrict__ bucketed, int nE, int nc, int chunk) {
    __shared__ int stage[STAGE_CAP];
    __shared__ int sc[256];
    __shared__ int lbeg[MAXNC];
    __shared__ int lcur[MAXNC];
    int b = blockIdx.x, t = threadIdx.x;

    int v0 = (2 * t < nc) ? hist[(size_t)b * nc + 2 * t] : 0;
    int v1 = (2 * t + 1 < nc) ? hist[(size_t)b * nc + 2 * t + 1] : 0;
    int s = v0 + v1;
    sc[t] = s;
    __syncthreads();
    for (int d = 1; d < 256; d <<= 1) {
        int x = (t >= d) ? sc[t - d] : 0;
        __syncthreads();
        sc[t] += x;
        __syncthreads();
    }
    int excl = sc[t] - s;
    if (2 * t < nc) { lbeg[2 * t] = excl; lcur[2 * t] = excl; }
    if (2 * t + 1 < nc) { lbeg[2 * t + 1] = excl + v0; lcur[2 * t + 1] = excl + v0; }
    __syncthreads();

    int c0 = b * chunk, c1 = min(nE, c0 + chunk);
    if (c1 > c0) {
        int nv = (c1 - c0) >> 2;
        const int4* d4 = (const int4*)(dst + c0);
        const int4* s4 = (const int4*)(src + c0);
        for (int i = t; i < nv; i += 256) {
            int4 dd = d4[i];
            int4 ss = s4[i];
            int pos;
            pos = atomicAdd(&lcur[dd.x >> 8], 1); stage[pos] = ss.x | ((dd.x & 255) << 17);
            pos = atomicAdd(&lcur[dd.y >> 8], 1); stage[pos] = ss.y | ((dd.y & 255) << 17);
            pos = atomicAdd(&lcur[dd.z >> 8], 1); stage[pos] = ss.z | ((dd.z & 255) << 17);
            pos = atomicAdd(&lcur[dd.w >> 8], 1); stage[pos] = ss.w | ((dd.w & 255) << 17);
        }
        int rem = (c1 - c0) & 3;
        if (t < rem) {
            int e = c0 + (nv << 2) + t;
            int d = dst[e];
            int pos = atomicAdd(&lcur[d >> 8], 1);
            stage[pos] = src[e] | ((d & 255) << 17);
        }
    }
    __syncthreads();

    for (int c = t; c < nc; c += 256) {
        int lo = lbeg[c];
        int cnt = lcur[c] - lo;
        int g = cbase[c] + offT[(size_t)c * NBLK + b];
        int padded = (cnt + 15) & ~15;
        for (int i = 0; i < padded; i += 4) {
            int4 v;
            v.x = (i + 0 < cnt) ? stage[lo + i + 0] : -1;
            v.y = (i + 1 < cnt) ? stage[lo + i + 1] : -1;
            v.z = (i + 2 < cnt) ? stage[lo + i + 2] : -1;
            v.w = (i + 3 < cnt) ? stage[lo + i + 3] : -1;
            *(int4*)(bucketed + g + i) = v;
        }
    }
}

// ---------------- pass D: within-bucket sort; csr stores BYTE offsets (s*32) ----------------
__global__ void k_fine(const int* __restrict__ bucketed, const int* __restrict__ cbase,
                       const int* __restrict__ rbase,
                       int* __restrict__ csr, int* __restrict__ rowstart,
                       float* __restrict__ dinv, int n) {
    __shared__ int cnt[256];
    __shared__ int lrs[512];
    __shared__ int cur[256];
    int cb = blockIdx.x, t = threadIdx.x;  // 512 threads
    int e0 = cbase[cb], e1 = cbase[cb + 1];
    int r0 = rbase[cb];
    if (t < 256) cnt[t] = 0;
    __syncthreads();
    int nv = (e1 - e0) >> 2;
    const int4* b4 = (const int4*)(bucketed + e0);
    for (int i = t; i < nv; i += 512) {
        int4 en = b4[i];
        if (en.x >= 0) atomicAdd(&cnt[(en.x >> 17) & 255], 1);
        if (en.y >= 0) atomicAdd(&cnt[(en.y >> 17) & 255], 1);
        if (en.z >= 0) atomicAdd(&cnt[(en.z >> 17) & 255], 1);
        if (en.w >= 0) atomicAdd(&cnt[(en.w >> 17) & 255], 1);
    }
    __syncthreads();
    int my = (t < 256) ? cnt[t] : 0;
    lrs[t] = my;
    __syncthreads();
    for (int d = 1; d < 512; d <<= 1) {
        int x = (t >= d) ? lrs[t - d] : 0;
        __syncthreads();
        lrs[t] += x;
        __syncthreads();
    }
    if (t < 256) {
        int excl = lrs[t] - my;
        int node = cb * 256 + t;
        if (node < n) {
            rowstart[node] = r0 + excl;
            dinv[node] = rsqrtf((float)(my + 1));
        }
        cur[t] = r0 + excl;
    }
    __syncthreads();
    for (int i = t; i < nv; i += 512) {
        int4 en = b4[i];
        int pos;
        if (en.x >= 0) { pos = atomicAdd(&cur[(en.x >> 17) & 255], 1); csr[pos] = (en.x & 0x1FFFF) << 5; }
        if (en.y >= 0) { pos = atomicAdd(&cur[(en.y >> 17) & 255], 1); csr[pos] = (en.y & 0x1FFFF) << 5; }
        if (en.z >= 0) { pos = atomicAdd(&cur[(en.z >> 17) & 255], 1); csr[pos] = (en.z & 0x1FFFF) << 5; }
        if (en.w >= 0) { pos = atomicAdd(&cur[(en.w >> 17) & 255], 1); csr[pos] = (en.w & 0x1FFFF) << 5; }
    }
}

// ---------------- prescale: xs = dinv * x (fp32) + bf16 shadow ----------------
__global__ void k_prescale(const float* __restrict__ x, const float* __restrict__ dinv,
                           float* __restrict__ xs, uint32* __restrict__ xsb, int n) {
    int i = blockIdx.x * blockDim.x + threadIdx.x;
    if (i >= n) return;
    float di = dinv[i];
    const float4* xp = (const float4*)(x + (size_t)i * 16);
    float4* op = (float4*)(xs + (size_t)i * 16);
    uint32 pk[8];
#pragma unroll
    for (int q = 0; q < 4; ++q) {
        float4 v = xp[q];
        v.x *= di; v.y *= di; v.z *= di; v.w *= di;
        op[q] = v;
        pk[q * 2 + 0] = pack2(v.x, v.y);
        pk[q * 2 + 1] = pack2(v.z, v.w);
    }
    uint4* bp = (uint4*)(xsb + (size_t)i * 8);
    bp[0] = make_uint4(pk[0], pk[1], pk[2], pk[3]);
    bp[1] = make_uint4(pk[4], pk[5], pk[6], pk[7]);
}

// ---------------- agg: wave/node, 16 slots x 4 lanes, batch-4 bf16 gathers ----------------
// csr holds byte offsets; per-lane base pre-offset by c*8 -> 1 add per gather.
__global__ void k_agg(const uint32* __restrict__ hb16, const int* __restrict__ csr,
                      const int* __restrict__ rowstart, float* __restrict__ agg, int n) {
    int wid = (blockIdx.x * blockDim.x + threadIdx.x) >> 6;
    if (wid >= n) return;
    int lane = threadIdx.x & 63;
    int q = lane >> 2;   // edge slot 0..15
    int c = lane & 3;    // feature quad
    int r0 = rowstart[wid], r1 = rowstart[wid + 1];
    int cnt = r1 - r0;
    const int* p = csr + r0 + q;
    int my = (cnt > q) ? ((cnt - q + 15) >> 4) : 0;
    const char* hbase = (const char*)hb16 + c * 8;  // per-lane byte base

    float av[4] = {0.f, 0.f, 0.f, 0.f};
    int t = 0;
    for (; t + 4 <= my; t += 4) {
        int o0 = __builtin_nontemporal_load(p + (t + 0) * 16);
        int o1 = __builtin_nontemporal_load(p + (t + 1) * 16);
        int o2 = __builtin_nontemporal_load(p + (t + 2) * 16);
        int o3 = __builtin_nontemporal_load(p + (t + 3) * 16);
        uint2 w0 = *(const uint2*)(hbase + (unsigned)o0);
        uint2 w1 = *(const uint2*)(hbase + (unsigned)o1);
        uint2 w2 = *(const uint2*)(hbase + (unsigned)o2);
        uint2 w3 = *(const uint2*)(hbase + (unsigned)o3);
        av[0] += (bf_lo(w0.x) + bf_lo(w1.x)) + (bf_lo(w2.x) + bf_lo(w3.x));
        av[1] += (bf_hi(w0.x) + bf_hi(w1.x)) + (bf_hi(w2.x) + bf_hi(w3.x));
        av[2] += (bf_lo(w0.y) + bf_lo(w1.y)) + (bf_lo(w2.y) + bf_lo(w3.y));
        av[3] += (bf_hi(w0.y) + bf_hi(w1.y)) + (bf_hi(w2.y) + bf_hi(w3.y));
    }
    if (t + 2 <= my) {
        int o0 = __builtin_nontemporal_load(p + (t + 0) * 16);
        int o1 = __builtin_nontemporal_load(p + (t + 1) * 16);
        uint2 w0 = *(const uint2*)(hbase + (unsigned)o0);
        uint2 w1 = *(const uint2*)(hbase + (unsigned)o1);
        av[0] += bf_lo(w0.x) + bf_lo(w1.x);
        av[1] += bf_hi(w0.x) + bf_hi(w1.x);
        av[2] += bf_lo(w0.y) + bf_lo(w1.y);
        av[3] += bf_hi(w0.y) + bf_hi(w1.y);
        t += 2;
    }
    if (t < my) {
        int o0 = __builtin_nontemporal_load(p + t * 16);
        uint2 w0 = *(const uint2*)(hbase + (unsigned)o0);
        av[0] += bf_lo(w0.x); av[1] += bf_hi(w0.x);
        av[2] += bf_lo(w0.y); av[3] += bf_hi(w0.y);
    }
#pragma unroll
    for (int m = 4; m <= 32; m <<= 1) {
#pragma unroll
        for (int j = 0; j < 4; ++j) av[j] += __shfl_xor(av[j], m);
    }
    if (q == 0) {
        vfloat4 o = {av[0], av[1], av[2], av[3]};
        __builtin_nontemporal_store(o, (vfloat4*)(agg + (size_t)wid * 16 + c * 4));
    }
}

// ---------------- post: 4 threads/node, GEMM + activation; writes fp32 + bf16 shadow ----------------
template <int MODE>
__global__ void k_post(const float* __restrict__ agg, const float* __restrict__ hin,
                       const int* __restrict__ rowstart, const float* __restrict__ dinv,
                       const float* __restrict__ Wa, const float* __restrict__ ba,
                       const float* __restrict__ Wb,
                       float* __restrict__ hout, uint32* __restrict__ hb16out, int n) {
    int idx = blockIdx.x * blockDim.x + threadIdx.x;
    int node = idx >> 2;
    if (node >= n) return;
    int t4 = idx & 3;
    int lane = threadIdx.x & 63;
    int lbase = lane & 60;

    float4 av = *(const float4*)(agg + (size_t)node * 16 + t4 * 4);
    float4 sv = *(const float4*)(hin + (size_t)node * 16 + t4 * 4);

    float a[16], s[16];
#pragma unroll
    for (int g = 0; g < 4; ++g) {
        a[g * 4 + 0] = __shfl(av.x, lbase + g);
        a[g * 4 + 1] = __shfl(av.y, lbase + g);
        a[g * 4 + 2] = __shfl(av.z, lbase + g);
        a[g * 4 + 3] = __shfl(av.w, lbase + g);
        s[g * 4 + 0] = __shfl(sv.x, lbase + g);
        s[g * 4 + 1] = __shfl(sv.y, lbase + g);
        s[g * 4 + 2] = __shfl(sv.z, lbase + g);
        s[g * 4 + 3] = __shfl(sv.w, lbase + g);
    }

    int fo = t4 * 4;
    float yv[4];
    if (MODE == 0) {
        float di = dinv[node];
#pragma unroll
        for (int k = 0; k < 16; ++k) a[k] = di * (a[k] + s[k]);
#pragma unroll
        for (int j = 0; j < 4; ++j) yv[j] = ba[fo + j];
#pragma unroll
        for (int k = 0; k < 16; ++k) {
            float4 w = *(const float4*)(Wa + k * 16 + fo);
            yv[0] += a[k] * w.x; yv[1] += a[k] * w.y;
            yv[2] += a[k] * w.z; yv[3] += a[k] * w.w;
        }
#pragma unroll
        for (int j = 0; j < 4; ++j) yv[j] = tanhf(yv[j]);
    } else {
        int cnt = rowstart[node + 1] - rowstart[node];
        float inv = 1.0f / fmaxf((float)cnt, 1.0f);
#pragma unroll
        for (int k = 0; k < 16; ++k) a[k] *= inv;
#pragma unroll
        for (int j = 0; j < 4; ++j) yv[j] = ba[fo + j];
#pragma unroll
        for (int k = 0; k < 16; ++k) {
            float4 wa = *(const float4*)(Wa + k * 16 + fo);
            float4 wb = *(const float4*)(Wb + k * 16 + fo);
            yv[0] += a[k] * wa.x + s[k] * wb.x;
            yv[1] += a[k] * wa.y + s[k] * wb.y;
            yv[2] += a[k] * wa.z + s[k] * wb.z;
            yv[3] += a[k] * wa.w + s[k] * wb.w;
        }
        float sq = yv[0] * yv[0] + yv[1] * yv[1] + yv[2] * yv[2] + yv[3] * yv[3];
        sq += __shfl_xor(sq, 1);
        sq += __shfl_xor(sq, 2);
        float nrm = fmaxf(sqrtf(sq), 1e-12f);
#pragma unroll
        for (int j = 0; j < 4; ++j) yv[j] /= nrm;
        if (MODE == 1) {
#pragma unroll
            for (int j = 0; j < 4; ++j) yv[j] = tanhf(yv[j]);
        }
    }
    *(float4*)(hout + (size_t)node * 16 + fo) = make_float4(yv[0], yv[1], yv[2], yv[3]);
    if (hb16out) {
        uint2 pk = make_uint2(pack2(yv[0], yv[1]), pack2(yv[2], yv[3]));
        *(uint2*)(hb16out + (size_t)node * 8 + t4 * 2) = pk;
    }
}

// ---------------- W2 pack: [k][out] fp32 -> [out][k/2] bf16-pair hi + lo residual ----------------
__global__ void k_wpack(const float* __restrict__ W2, uint32* __restrict__ hi,
                        uint32* __restrict__ lo) {
    int u = blockIdx.x * blockDim.x + threadIdx.x;  // 8192 = 128 outs x 64 k-pairs
    if (u >= 8192) return;
    int outc = u >> 6;
    int ui = u & 63;
    float a = W2[(size_t)(2 * ui) * 128 + outc];
    float b = W2[(size_t)(2 * ui + 1) * 128 + outc];
    uint32 h = pack2(a, b);
    float ra = a - bf_lo(h);
    float rb = b - bf_hi(h);
    hi[u] = h;
    lo[u] = pack2(ra, rb);
}

// ---------------- Fused MLP v10: layer1 VALU + layer2 MFMA bf16 hi/lo split ----------------
#define MLP_NODES 64
__global__ __launch_bounds__(256)
void k_mlp(const float* __restrict__ h3,
           const float* __restrict__ W1, const float* __restrict__ b1,
           const uint32* __restrict__ W2h, const uint32* __restrict__ W2l,
           const float* __restrict__ b2,
           const float* __restrict__ W3, const float* __restrict__ b3,
           float* __restrict__ out, int n) {
    __shared__ __align__(16) uint32 t1h[64][68];
    __shared__ __align__(16) uint32 t1l[64][68];
    __shared__ float hpart[MLP_NODES][5];

    int t = threadIdx.x;
    int w = t >> 6;
    int l = t & 63;
    int ow = __builtin_amdgcn_readfirstlane(w * 32);
    int node0 = blockIdx.x * MLP_NODES;
    int node = node0 + l;
    int nodec = min(node, n - 1);
    int cl = l & 15, kg = l >> 4;

    // ---- layer 1: VALU, scalar-datapath W1 ----
    {
        float h[16];
        const float4* hp = (const float4*)(h3 + (size_t)nodec * 16);
#pragma unroll
        for (int q = 0; q < 4; ++q) {
            float4 v = hp[q];
            h[q * 4 + 0] = v.x; h[q * 4 + 1] = v.y; h[q * 4 + 2] = v.z; h[q * 4 + 3] = v.w;
        }
        float acc[32];
        const float* bp = b1 + ow;
#pragma unroll
        for (int j = 0; j < 32; ++j) acc[j] = bp[j];
#pragma unroll
        for (int k = 0; k < 16; ++k) {
            const float* wr = W1 + k * 128 + ow;
            float hk = h[k];
#pragma unroll
            for (int j = 0; j < 32; ++j) acc[j] += hk * wr[j];
        }
#pragma unroll
        for (int j = 0; j < 32; j += 2) {
            float a0 = fmaxf(acc[j], 0.f), a1 = fmaxf(acc[j + 1], 0.f);
            uint32 hi = pack2(a0, a1);
            float r0 = a0 - bf_lo(hi);
            float r1 = a1 - bf_hi(hi);
            int ui = (ow + j) >> 1;
            t1h[l][ui] = hi;
            t1l[l][ui] = pack2(r0, r1);
        }
    }

    // ---- B fragments for this wave's 32 outs (hi/lo) ----
    uint4 bh0[4], bl0[4], bh1[4], bl1[4];
    {
        int c0 = ow + cl, c1 = ow + 16 + cl;
        const uint4* ph0 = (const uint4*)(W2h + (size_t)c0 * 64);
        const uint4* pl0 = (const uint4*)(W2l + (size_t)c0 * 64);
        const uint4* ph1 = (const uint4*)(W2h + (size_t)c1 * 64);
        const uint4* pl1 = (const uint4*)(W2l + (size_t)c1 * 64);
#pragma unroll
        for (int ks = 0; ks < 4; ++ks) {
            bh0[ks] = ph0[ks * 4 + kg];
            bl0[ks] = pl0[ks * 4 + kg];
            bh1[ks] = ph1[ks * 4 + kg];
            bl1[ks] = pl1[ks * 4 + kg];
        }
    }
    float b2v0 = b2[ow + cl], b2v1 = b2[ow + 16 + cl];
    float w3v0 = W3[ow + cl], w3v1 = W3[ow + 16 + cl];
    __syncthreads();

    // ---- layer 2 MFMA + layer 3 reduce, per 16-node group ----
    for (int ng = 0; ng < 4; ++ng) {
        int an = ng * 16 + cl;
        const uint4* pah = (const uint4*)(&t1h[an][0]);
        const uint4* pal = (const uint4*)(&t1l[an][0]);
        uint4 ahu[4], alu[4];
#pragma unroll
        for (int ks = 0; ks < 4; ++ks) {
            ahu[ks] = pah[ks * 4 + kg];
            alu[ks] = pal[ks * 4 + kg];
        }
        f32x4 acc0 = {b2v0, b2v0, b2v0, b2v0};
        f32x4 acc1 = {b2v1, b2v1, b2v1, b2v1};
#pragma unroll
        for (int ks = 0; ks < 4; ++ks) {
            bf16x8v a_h = as_bf(ahu[ks]);
            bf16x8v a_l = as_bf(alu[ks]);
            acc0 = __builtin_amdgcn_mfma_f32_16x16x32_bf16(a_h, as_bf(bh0[ks]), acc0, 0, 0, 0);
            acc0 = __builtin_amdgcn_mfma_f32_16x16x32_bf16(a_h, as_bf(bl0[ks]), acc0, 0, 0, 0);
            acc0 = __builtin_amdgcn_mfma_f32_16x16x32_bf16(a_l, as_bf(bh0[ks]), acc0, 0, 0, 0);
            acc1 = __builtin_amdgcn_mfma_f32_16x16x32_bf16(a_h, as_bf(bh1[ks]), acc1, 0, 0, 0);
            acc1 = __builtin_amdgcn_mfma_f32_16x16x32_bf16(a_h, as_bf(bl1[ks]), acc1, 0, 0, 0);
            acc1 = __builtin_amdgcn_mfma_f32_16x16x32_bf16(a_l, as_bf(bh1[ks]), acc1, 0, 0, 0);
        }
        float pj[4];
#pragma unroll
        for (int j = 0; j < 4; ++j)
            pj[j] = fmaxf(acc0[j], 0.f) * w3v0 + fmaxf(acc1[j], 0.f) * w3v1;
#pragma unroll
        for (int m = 1; m <= 8; m <<= 1) {
#pragma unroll
            for (int j = 0; j < 4; ++j) pj[j] += __shfl_xor(pj[j], m);
        }
        if (cl == 0) {
#pragma unroll
            for (int j = 0; j < 4; ++j) hpart[ng * 16 + kg * 4 + j][w] = pj[j];
        }
    }
    __syncthreads();
    if (w == 0 && node < n) {
        out[node] = hpart[l][0] + hpart[l][1] + hpart[l][2] + hpart[l][3] + b3[0];
    }
}

// ---------------- launch ----------------
extern "C" void kernel_launch(void* const* d_in, const int* in_sizes, int n_in,
                              void* d_out, int out_size, void* d_ws, size_t ws_size,
                              hipStream_t stream) {
    const float* x = (const float*)d_in[0];
    const int* ei = (const int*)d_in[1];
    const float* W_gcn = (const float*)d_in[2];
    const float* b_gcn = (const float*)d_in[3];
    const float* Wl1 = (const float*)d_in[4];
    const float* bl1 = (const float*)d_in[5];
    const float* Wr1 = (const float*)d_in[6];
    const float* Wl2 = (const float*)d_in[7];
    const float* bl2 = (const float*)d_in[8];
    const float* Wr2 = (const float*)d_in[9];
    const float* W1 = (const float*)d_in[10];
    const float* b1 = (const float*)d_in[11];
    const float* W2 = (const float*)d_in[12];
    const float* b2 = (const float*)d_in[13];
    const float* W3 = (const float*)d_in[14];
    const float* b3 = (const float*)d_in[15];

    const int N = in_sizes[0] / 16;
    const int E = in_sizes[1] / 2;
    const int NC = (N + 255) >> 8;
    const int chunk = (((E + NBLK - 1) / NBLK) + 3) & ~3;
    const int* src = ei;
    const int* dst = ei + E;

    char* w = (char*)d_ws;
    auto alloc = [&](size_t bytes) {
        void* p = (void*)w;
        w += (bytes + 255) & ~(size_t)255;
        return p;
    };
    int* hist = (int*)alloc((size_t)NBLK * NC * 4);
    int* offT = (int*)alloc((size_t)NBLK * NC * 4);
    int* totPad = (int*)alloc((size_t)NC * 4);
    int* totReal = (int*)alloc((size_t)NC * 4);
    int* cbase = (int*)alloc((size_t)(NC + 1) * 4);
    int* rbase = (int*)alloc((size_t)NC * 4);
    int* rowstart = (int*)alloc((size_t)(N + 1) * 4);
    float* dinv = (float*)alloc((size_t)N * 4);
    int* bucketed = (int*)alloc(((size_t)E + (size_t)NBLK * NC * 16) * 4);
    int* csr = (int*)alloc((size_t)E * 4);
    float* xs = (float*)alloc((size_t)N * 16 * 4);
    float* agg = (float*)alloc((size_t)N * 16 * 4);
    float* h1 = (float*)alloc((size_t)N * 16 * 4);
    float* h2 = (float*)alloc((size_t)N * 16 * 4);
    float* h3 = (float*)alloc((size_t)N * 16 * 4);
    uint32* xsb = (uint32*)alloc((size_t)N * 8 * 4);
    uint32* h1b = (uint32*)alloc((size_t)N * 8 * 4);
    uint32* h2b = (uint32*)alloc((size_t)N * 8 * 4);
    uint32* w2h = (uint32*)alloc((size_t)128 * 64 * 4);
    uint32* w2l = (uint32*)alloc((size_t)128 * 64 * 4);

    k_wpack<<<32, 256, 0, stream>>>(W2, w2h, w2l);
    k_hist<<<NBLK, 256, 0, stream>>>(dst, hist, E, NC, chunk);
    k_scanA<<<NC, 256, 0, stream>>>(hist, offT, totPad, totReal, NC);
    k_scanB<<<1, 512, 0, stream>>>(totPad, totReal, cbase, rbase, rowstart, E, NC, N);
    k_fill<<<NBLK, 256, 0, stream>>>(src, dst, hist, offT, cbase, bucketed, E, NC, chunk);
    k_fine<<<NC, 512, 0, stream>>>(bucketed, cbase, rbase, csr, rowstart, dinv, N);

    int blk = 256;
    int ngrid = (N + blk - 1) / blk;
    long long agg_threads = (long long)N * 64;
    int agrid = (int)((agg_threads + blk - 1) / blk);
    int pgrid = (int)(((long long)N * 4 + blk - 1) / blk);

    k_prescale<<<ngrid, blk, 0, stream>>>(x, dinv, xs, xsb, N);

    // GCN
    k_agg<<<agrid, blk, 0, stream>>>(xsb, csr, rowstart, agg, N);
    k_post<0><<<pgrid, blk, 0, stream>>>(agg, xs, rowstart, dinv, W_gcn, b_gcn, W_gcn, h1, h1b, N);
    // SAGE 1
    k_agg<<<agrid, blk, 0, stream>>>(h1b, csr, rowstart, agg, N);
    k_post<1><<<pgrid, blk, 0, stream>>>(agg, h1, rowstart, dinv, Wl1, bl1, Wr1, h2, h2b, N);
    // SAGE 2
    k_agg<<<agrid, blk, 0, stream>>>(h2b, csr, rowstart, agg, N);
    k_post<2><<<pgrid, blk, 0, stream>>>(agg, h2, rowstart, dinv, Wl2, bl2, Wr2, h3, (uint32*)nullptr, N);

    int mgrid = (N + MLP_NODES - 1) / MLP_NODES;
    k_mlp<<<mgrid, blk, 0, stream>>>(h3, W1, b1, w2h, w2l, b2, W3, b3, (float*)d_out, N);
}